// Round 1
// 1016.561 us; speedup vs baseline: 1.0839x; 1.0839x over previous
//
#include <hip/hip_runtime.h>
#include <hip/hip_bf16.h>
#include <cstdint>
#include <cstddef>

#define B_ 64
#define S_ 4096
#define E_ 512
#define H_ 512
#define NEGV (-1.0e9f)

typedef short s8v __attribute__((ext_vector_type(8)));
typedef float f4v __attribute__((ext_vector_type(4)));

// native bf16 RNE conversion: compiler emits v_cvt_pk_bf16_f32 for pairs.
// hi/lo split is self-correcting (lo = rn(x - hi)), so exact hi rounding mode
// does not matter for the reconstructed product.
__device__ __forceinline__ unsigned short bf_rn(float x) {
    return __builtin_bit_cast(unsigned short, __float2bfloat16(x));
}
__device__ __forceinline__ float bf_up(unsigned short h) {
    unsigned u = ((unsigned)h) << 16;
    return __builtin_bit_cast(float, u);
}

// ---- W_enc -> transposed bf16 hi/lo: Wt[n][k] ----
__global__ void prep_w(const float* __restrict__ W_enc,
                       unsigned short* __restrict__ Wt_hi,
                       unsigned short* __restrict__ Wt_lo) {
    int n = blockIdx.x;
    for (int it = 0; it < 2; ++it) {
        int k = threadIdx.x + it * 256;
        float x = W_enc[(size_t)k * H_ + n];
        unsigned short h = bf_rn(x);
        float r = x - bf_up(h);
        Wt_hi[(size_t)n * E_ + k] = h;
        Wt_lo[(size_t)n * E_ + k] = bf_rn(r);
    }
}

// ---- decoded = dec @ W_dec (fp32, tiny). grid (4, B): 256 blocks for latency. ----
__global__ void dec_proj(const float* __restrict__ dec,
                         const float* __restrict__ W_dec,
                         float* __restrict__ decoded) {
    __shared__ float sd[512];
    __shared__ float part[128];
    int b = blockIdx.y;
    int h0 = blockIdx.x * 128;
    int tid = threadIdx.x;
    sd[tid]       = dec[b * 512 + tid];
    sd[tid + 256] = dec[b * 512 + tid + 256];
    __syncthreads();
    int h = h0 + (tid & 127);
    int dh = tid >> 7;            // split d-range across thread halves
    float a = 0.f;
#pragma unroll 8
    for (int d = dh * 256; d < dh * 256 + 256; ++d)
        a += sd[d] * W_dec[(size_t)d * 512 + h];
    if (dh) part[tid & 127] = a;
    __syncthreads();
    if (!dh) decoded[(size_t)b * 512 + h] = a + part[tid];
}

// ---- fused: logits[b,s] += sum_h tanh((enc@W_enc)[s,h] + decoded[b,h]) * W_out[h]
// bf16x3 split MFMA GEMM, 128x128 tile, BK=32, 4 waves (2x2), 4x4 of 16x16x32 each
__global__ __launch_bounds__(256, 2)
void logits_gemm(const float* __restrict__ enc,
                 const unsigned short* __restrict__ Wt_hi,
                 const unsigned short* __restrict__ Wt_lo,
                 const float* __restrict__ decoded,
                 const float* __restrict__ W_out,
                 float* __restrict__ logits) {
    const int LDA = 40;  // 32 + 8 pad: frag reads land 2-way bank aliased (free)
    __shared__ __align__(16) unsigned short As_hi[128 * 40];
    __shared__ __align__(16) unsigned short As_lo[128 * 40];
    __shared__ __align__(16) unsigned short Bs_hi[128 * 40];
    __shared__ __align__(16) unsigned short Bs_lo[128 * 40];

    // XCD-bijective swizzle: HW assigns block p -> XCD p%8. Give each XCD a
    // contiguous rt range and keep the 4 ct-siblings of one A-tile adjacent
    // on the SAME XCD so the A tile is fetched into that L2 exactly once.
    int bx = blockIdx.x;                // 8192 blocks = 2048 rt x 4 ct
    int xcd = bx & 7, idx = bx >> 3;    // idx: 0..1023 within XCD
    int rt = xcd * 256 + (idx >> 2);    // 256 row-tiles per XCD
    int ct = idx & 3;
    int r0 = rt * 128;
    int b  = r0 >> 12;                  // S=4096 rows per batch, 128 | 4096
    int sb = r0 & 4095;
    int nb0 = ct * 128;

    int tid  = threadIdx.x;
    int lane = tid & 63, wid = tid >> 6;
    int wr = wid >> 1, wc = wid & 1;
    int quad = lane >> 4, cl = lane & 15;

    f4v acc[4][4];
#pragma unroll
    for (int i = 0; i < 4; ++i)
#pragma unroll
        for (int j = 0; j < 4; ++j) acc[i][j] = (f4v)0.f;

    int a_k4 = tid & 7, a_m = tid >> 3;   // A staging: float4 per thread
    int b_k8 = tid & 3, b_n = tid >> 2;   // B staging: 8 bf16 per thread

    for (int k0 = 0; k0 < 512; k0 += 32) {
        __syncthreads();
        // stage A: 128 rows x 32 k, fp32 -> hi/lo bf16 (native cvt, ~2x less VALU)
#pragma unroll
        for (int mm = 0; mm < 4; ++mm) {
            int m = a_m + mm * 32;
            float4 v = *(const float4*)(enc + (size_t)(r0 + m) * E_ + k0 + a_k4 * 4);
            unsigned short h0 = bf_rn(v.x), h1 = bf_rn(v.y), h2 = bf_rn(v.z), h3 = bf_rn(v.w);
            unsigned short l0 = bf_rn(v.x - bf_up(h0)), l1 = bf_rn(v.y - bf_up(h1));
            unsigned short l2 = bf_rn(v.z - bf_up(h2)), l3 = bf_rn(v.w - bf_up(h3));
            uint2 ph, pl;
            ph.x = (unsigned)h0 | ((unsigned)h1 << 16); ph.y = (unsigned)h2 | ((unsigned)h3 << 16);
            pl.x = (unsigned)l0 | ((unsigned)l1 << 16); pl.y = (unsigned)l2 | ((unsigned)l3 << 16);
            *(uint2*)&As_hi[m * LDA + a_k4 * 4] = ph;
            *(uint2*)&As_lo[m * LDA + a_k4 * 4] = pl;
        }
        // stage B: 128 n x 32 k from pre-split Wt[n][k]
#pragma unroll
        for (int nn = 0; nn < 2; ++nn) {
            int n = b_n + nn * 64;
            *(uint4*)&Bs_hi[n * LDA + b_k8 * 8] =
                *(const uint4*)(Wt_hi + (size_t)(nb0 + n) * E_ + k0 + b_k8 * 8);
            *(uint4*)&Bs_lo[n * LDA + b_k8 * 8] =
                *(const uint4*)(Wt_lo + (size_t)(nb0 + n) * E_ + k0 + b_k8 * 8);
        }
        __syncthreads();

        s8v ah[4], al[4], bh[4], bl[4];
#pragma unroll
        for (int i = 0; i < 4; ++i) {
            int row = wr * 64 + i * 16 + cl;
            ah[i] = *(const s8v*)&As_hi[row * LDA + quad * 8];
            al[i] = *(const s8v*)&As_lo[row * LDA + quad * 8];
        }
#pragma unroll
        for (int j = 0; j < 4; ++j) {
            int col = wc * 64 + j * 16 + cl;
            bh[j] = *(const s8v*)&Bs_hi[col * LDA + quad * 8];
            bl[j] = *(const s8v*)&Bs_lo[col * LDA + quad * 8];
        }
        // 3 passes, dependent MFMAs 16 apart
#pragma unroll
        for (int i = 0; i < 4; ++i)
#pragma unroll
            for (int j = 0; j < 4; ++j)
                acc[i][j] = __builtin_amdgcn_mfma_f32_16x16x32_bf16(ah[i], bh[j], acc[i][j], 0, 0, 0);
#pragma unroll
        for (int i = 0; i < 4; ++i)
#pragma unroll
            for (int j = 0; j < 4; ++j)
                acc[i][j] = __builtin_amdgcn_mfma_f32_16x16x32_bf16(ah[i], bl[j], acc[i][j], 0, 0, 0);
#pragma unroll
        for (int i = 0; i < 4; ++i)
#pragma unroll
            for (int j = 0; j < 4; ++j)
                acc[i][j] = __builtin_amdgcn_mfma_f32_16x16x32_bf16(al[i], bh[j], acc[i][j], 0, 0, 0);
    }

    // epilogue: +decoded, tanh, *W_out, reduce over this tile's 128 h-cols
    float dcol[4], wcol[4];
#pragma unroll
    for (int j = 0; j < 4; ++j) {
        int h = nb0 + wc * 64 + j * 16 + cl;
        dcol[j] = decoded[b * 512 + h];
        wcol[j] = W_out[h];
    }
#pragma unroll
    for (int i = 0; i < 4; ++i) {
        float rs[4] = {0.f, 0.f, 0.f, 0.f};
#pragma unroll
        for (int j = 0; j < 4; ++j) {
#pragma unroll
            for (int r = 0; r < 4; ++r) {
                float x = acc[i][j][r] + dcol[j];
                float e = __expf(2.0f * x);          // inf-safe tanh
                float t = 1.0f - 2.0f / (e + 1.0f);
                rs[r] += t * wcol[j];
            }
        }
#pragma unroll
        for (int r = 0; r < 4; ++r) {
            rs[r] += __shfl_xor(rs[r], 1, 64);
            rs[r] += __shfl_xor(rs[r], 2, 64);
            rs[r] += __shfl_xor(rs[r], 4, 64);
            rs[r] += __shfl_xor(rs[r], 8, 64);
        }
        if (cl == 0) {
            int srow = sb + wr * 64 + i * 16 + quad * 4;
#pragma unroll
            for (int r = 0; r < 4; ++r)
                atomicAdd(&logits[(size_t)b * S_ + srow + r], rs[r]);
        }
    }
}

// ---- fused masked softmax + attn: one block per batch row.
// Builds an explicit survivor list (p > 1e-8) in LDS, then reads ONLY those
// enc rows. Structural skip -- no dependence on branch codegen. Writes probs
// and attn fully (no output memset needed).
__global__ __launch_bounds__(256)
void softmax_attn(const float* __restrict__ logits,
                  const int* __restrict__ mask,
                  const float* __restrict__ enc,
                  float* __restrict__ probs,
                  float* __restrict__ attn) {
    __shared__ float red[4];
    __shared__ int cnt;
    __shared__ int   sidx[4096];
    __shared__ float spv[4096];
    int b = blockIdx.x, tid = threadIdx.x;
    int wid = tid >> 6, lane = tid & 63;
    if (tid == 0) cnt = 0;
    float xs[16];
    float m = -INFINITY;
#pragma unroll
    for (int t = 0; t < 16; ++t) {
        int s = tid + t * 256;
        float x = logits[(size_t)b * S_ + s];
        if (mask[b * S_ + s] == 0) x = NEGV;
        xs[t] = x;
        m = fmaxf(m, x);
    }
#pragma unroll
    for (int off = 32; off >= 1; off >>= 1) m = fmaxf(m, __shfl_xor(m, off, 64));
    if (lane == 0) red[wid] = m;
    __syncthreads();
    m = fmaxf(fmaxf(red[0], red[1]), fmaxf(red[2], red[3]));
    float sum = 0.f;
#pragma unroll
    for (int t = 0; t < 16; ++t) { xs[t] = __expf(xs[t] - m); sum += xs[t]; }
#pragma unroll
    for (int off = 32; off >= 1; off >>= 1) sum += __shfl_xor(sum, off, 64);
    __syncthreads();
    if (lane == 0) red[wid] = sum;
    __syncthreads();
    sum = red[0] + red[1] + red[2] + red[3];
    float inv = 1.0f / sum;
#pragma unroll
    for (int t = 0; t < 16; ++t) {
        int s = tid + t * 256;
        float p = xs[t] * inv;
        probs[(size_t)b * S_ + s] = p;
        if (p > 1e-8f) {                 // skipped mass < 4096*1e-8
            int k = atomicAdd(&cnt, 1);
            sidx[k] = s;
            spv[k]  = p;
        }
    }
    __syncthreads();
    int n = cnt;
    int e0 = tid * 2;
    float a0 = 0.f, a1 = 0.f;
    const float* ebase = enc + (size_t)b * S_ * E_ + e0;
    for (int i = 0; i < n; ++i) {
        float p = spv[i];
        const float2 v = *(const float2*)(ebase + (size_t)sidx[i] * E_);
        a0 += p * v.x;
        a1 += p * v.y;
    }
    attn[b * E_ + e0]     = a0;
    attn[b * E_ + e0 + 1] = a1;
}

extern "C" void kernel_launch(void* const* d_in, const int* in_sizes, int n_in,
                              void* d_out, int out_size, void* d_ws, size_t ws_size,
                              hipStream_t stream) {
    const float* enc   = (const float*)d_in[0];
    const float* dec   = (const float*)d_in[1];
    const int*   mask  = (const int*)d_in[2];
    const float* W_enc = (const float*)d_in[3];
    const float* W_dec = (const float*)d_in[4];
    const float* W_out = (const float*)d_in[5];

    char* ws = (char*)d_ws;
    unsigned short* Wt_hi   = (unsigned short*)(ws);             // 512 KB
    unsigned short* Wt_lo   = (unsigned short*)(ws + 524288);    // 512 KB
    float*          decoded = (float*)(ws + 1048576);            // 128 KB
    float*          logits  = (float*)(ws + 1179648);            // 1 MB

    float* attn  = (float*)d_out;               // [64,512]
    float* probs = (float*)d_out + B_ * E_;     // [64,4096]

    hipMemsetAsync(logits, 0, (size_t)B_ * S_ * sizeof(float), stream);

    prep_w<<<512, 256, 0, stream>>>(W_enc, Wt_hi, Wt_lo);
    dec_proj<<<dim3(4, B_), 256, 0, stream>>>(dec, W_dec, decoded);
    logits_gemm<<<(B_ * S_ / 128) * 4, 256, 0, stream>>>(enc, Wt_hi, Wt_lo, decoded, W_out, logits);
    softmax_attn<<<B_, 256, 0, stream>>>(logits, mask, enc, probs, attn);
}